// Round 1
// baseline (90.353 us; speedup 1.0000x reference)
//
#include <hip/hip_runtime.h>
#include <math.h>

// Tropical (min-plus) matmul: out[b,o] = min_j (x[b,j] + w[o,j])
// x: [512, 512] f32, w: [1024, 512] f32, out: [512, 1024] f32
//
// VALU-bound: 2 ops per (b,o,j) = 537M lane-ops -> ~6.8us floor at 78.6 Tops/s.
// 256 blocks (16 x-tiles x 16 o-tiles) -> 1 block per CU on 256 CUs.
// Block: 256 threads, tile 32(b) x 64(o), thread tile 2x4, K-chunk 64.

#define B_    512
#define IN_   512
#define OUT_  1024
#define TB    32   // b-tile per block
#define TO    64   // o-tile per block
#define BK    64   // k chunk
#define XPAD  34   // even -> 8B-aligned float2 reads; write conflicts 4-way only
#define OPAD  68   // 68*4=272B, 272%16==0 -> 16B-aligned float4 reads

__global__ __launch_bounds__(256) void tropical_kernel(
    const float* __restrict__ x, const float* __restrict__ w,
    float* __restrict__ out)
{
    __shared__ float xs[BK * XPAD];  // xs[j][b]  (transposed)
    __shared__ float ws[BK * OPAD];  // ws[j][o]  (transposed)

    const int tid = threadIdx.x;
    const int m  = tid & 15;   // staging: j-group (jj = 4*m)
    const int q  = tid >> 4;   // staging: row-group
    const int jj = m * 4;

    const int b0 = blockIdx.x * TB;
    const int o0 = blockIdx.y * TO;

    const int to = tid & 15;   // compute: o group (4 outputs at o0 + 4*to)
    const int tb = tid >> 4;   // compute: b group (2 outputs at b0 + 2*tb)

    float acc[2][4];
#pragma unroll
    for (int i = 0; i < 2; ++i)
#pragma unroll
        for (int j = 0; j < 4; ++j)
            acc[i][j] = INFINITY;

    for (int k0 = 0; k0 < IN_; k0 += BK) {
        // ---- stage x tile: 32 rows x 64 k, transpose into xs[j][b] ----
#pragma unroll
        for (int it = 0; it < 2; ++it) {
            const int b = q + it * 16;
            const float4 v = *(const float4*)&x[(size_t)(b0 + b) * IN_ + k0 + jj];
            xs[(jj + 0) * XPAD + b] = v.x;
            xs[(jj + 1) * XPAD + b] = v.y;
            xs[(jj + 2) * XPAD + b] = v.z;
            xs[(jj + 3) * XPAD + b] = v.w;
        }
        // ---- stage w tile: 64 rows x 64 k, transpose into ws[j][o] ----
#pragma unroll
        for (int it = 0; it < 4; ++it) {
            const int o = q + it * 16;
            const float4 v = *(const float4*)&w[(size_t)(o0 + o) * IN_ + k0 + jj];
            ws[(jj + 0) * OPAD + o] = v.x;
            ws[(jj + 1) * OPAD + o] = v.y;
            ws[(jj + 2) * OPAD + o] = v.z;
            ws[(jj + 3) * OPAD + o] = v.w;
        }
        __syncthreads();

        // ---- main loop: 16 VALU (8 add + 8 min) per j per thread ----
#pragma unroll 16
        for (int j = 0; j < BK; ++j) {
            const float2 xv = *(const float2*)&xs[j * XPAD + tb * 2];
            const float4 wv = *(const float4*)&ws[j * OPAD + to * 4];
            acc[0][0] = fminf(acc[0][0], xv.x + wv.x);
            acc[0][1] = fminf(acc[0][1], xv.x + wv.y);
            acc[0][2] = fminf(acc[0][2], xv.x + wv.z);
            acc[0][3] = fminf(acc[0][3], xv.x + wv.w);
            acc[1][0] = fminf(acc[1][0], xv.y + wv.x);
            acc[1][1] = fminf(acc[1][1], xv.y + wv.y);
            acc[1][2] = fminf(acc[1][2], xv.y + wv.z);
            acc[1][3] = fminf(acc[1][3], xv.y + wv.w);
        }
        __syncthreads();
    }

    // ---- epilogue: 2 coalesced float4 stores ----
#pragma unroll
    for (int i = 0; i < 2; ++i) {
        const int b = b0 + tb * 2 + i;
        float4 v;
        v.x = acc[i][0]; v.y = acc[i][1]; v.z = acc[i][2]; v.w = acc[i][3];
        *(float4*)&out[(size_t)b * OUT_ + o0 + to * 4] = v;
    }
}

extern "C" void kernel_launch(void* const* d_in, const int* in_sizes, int n_in,
                              void* d_out, int out_size, void* d_ws, size_t ws_size,
                              hipStream_t stream) {
    const float* x = (const float*)d_in[0];   // [512, 512]
    const float* w = (const float*)d_in[1];   // [1024, 512]
    float* out = (float*)d_out;               // [512, 1024]

    dim3 grid(B_ / TB, OUT_ / TO);            // 16 x 16 = 256 blocks
    tropical_kernel<<<grid, 256, 0, stream>>>(x, w, out);
}

// Round 2
// 80.263 us; speedup vs baseline: 1.1257x; 1.1257x over previous
//
#include <hip/hip_runtime.h>
#include <math.h>

// Tropical (min-plus) matmul: out[b,o] = min_j (x[b,j] + w[o,j])
// x: [512, 512] f32, w: [1024, 512] f32, out: [512, 1024] f32
//
// VALU-bound (no min-plus MFMA; no fp32 MFMA on CDNA4): 537M lane-ops,
// floor ~5-7us at 78.6 T ops/s. R1 evidence: kernel dispatch <40us (absent
// from rocprof top-5), dur_us 90 dominated by 2x42us harness poison fills.
// R2: 512 blocks (2 blocks/CU, 2 waves/SIMD) to overlap staging with compute
// across independent blocks; tile 32x32, thread tile 2x2.

#define B_    512
#define IN_   512
#define OUT_  1024
#define TB    32   // b-tile per block
#define TO    32   // o-tile per block
#define BK    64   // k chunk
#define PAD   34   // even -> 8B-aligned float2 reads; 136B row stride

__global__ __launch_bounds__(256) void tropical_kernel(
    const float* __restrict__ x, const float* __restrict__ w,
    float* __restrict__ out)
{
    __shared__ float xs[BK * PAD];  // xs[j][b]  (transposed)
    __shared__ float ws[BK * PAD];  // ws[j][o]  (transposed)

    const int tid = threadIdx.x;
    const int m  = tid & 15;   // staging: j-group (jj = 4*m)
    const int q  = tid >> 4;   // staging: row 0..15 (+16 on second iter)
    const int jj = m * 4;

    const int b0 = blockIdx.x * TB;
    const int o0 = blockIdx.y * TO;

    const int to = tid & 15;   // compute: 2 outputs at o0 + 2*to
    const int tb = tid >> 4;   // compute: 2 rows    at b0 + 2*tb

    float acc[2][2];
#pragma unroll
    for (int i = 0; i < 2; ++i)
#pragma unroll
        for (int j = 0; j < 2; ++j)
            acc[i][j] = INFINITY;

    for (int k0 = 0; k0 < IN_; k0 += BK) {
        // ---- stage x tile: 32 rows x 64 k, transposed into xs[j][b] ----
#pragma unroll
        for (int it = 0; it < 2; ++it) {
            const int b = q + it * 16;
            const float4 v = *(const float4*)&x[(size_t)(b0 + b) * IN_ + k0 + jj];
            xs[(jj + 0) * PAD + b] = v.x;
            xs[(jj + 1) * PAD + b] = v.y;
            xs[(jj + 2) * PAD + b] = v.z;
            xs[(jj + 3) * PAD + b] = v.w;
        }
        // ---- stage w tile: 32 rows x 64 k, transposed into ws[j][o] ----
#pragma unroll
        for (int it = 0; it < 2; ++it) {
            const int o = q + it * 16;
            const float4 v = *(const float4*)&w[(size_t)(o0 + o) * IN_ + k0 + jj];
            ws[(jj + 0) * PAD + o] = v.x;
            ws[(jj + 1) * PAD + o] = v.y;
            ws[(jj + 2) * PAD + o] = v.z;
            ws[(jj + 3) * PAD + o] = v.w;
        }
        __syncthreads();

        // ---- main loop: 4 adds (packable) + 4 mins per j per thread ----
#pragma unroll 16
        for (int j = 0; j < BK; ++j) {
            const float2 xv = *(const float2*)&xs[j * PAD + tb * 2];
            const float2 wv = *(const float2*)&ws[j * PAD + to * 2];
            acc[0][0] = fminf(acc[0][0], xv.x + wv.x);
            acc[0][1] = fminf(acc[0][1], xv.x + wv.y);
            acc[1][0] = fminf(acc[1][0], xv.y + wv.x);
            acc[1][1] = fminf(acc[1][1], xv.y + wv.y);
        }
        __syncthreads();
    }

    // ---- epilogue: 2 float2 stores ----
#pragma unroll
    for (int i = 0; i < 2; ++i) {
        const int b = b0 + tb * 2 + i;
        float2 v;
        v.x = acc[i][0]; v.y = acc[i][1];
        *(float2*)&out[(size_t)b * OUT_ + o0 + to * 2] = v;
    }
}

extern "C" void kernel_launch(void* const* d_in, const int* in_sizes, int n_in,
                              void* d_out, int out_size, void* d_ws, size_t ws_size,
                              hipStream_t stream) {
    const float* x = (const float*)d_in[0];   // [512, 512]
    const float* w = (const float*)d_in[1];   // [1024, 512]
    float* out = (float*)d_out;               // [512, 1024]

    dim3 grid(B_ / TB, OUT_ / TO);            // 16 x 32 = 512 blocks
    tropical_kernel<<<grid, 256, 0, stream>>>(x, w, out);
}

// Round 3
// 73.949 us; speedup vs baseline: 1.2218x; 1.0854x over previous
//
#include <hip/hip_runtime.h>
#include <math.h>

// Tropical (min-plus) matmul: out[b,o] = min_j (x[b,j] + w[o,j])
// x: [512, 512] f32, w: [1024, 512] f32, out: [512, 1024] f32
//
// VALU-bound (no min-plus MFMA; no fp32 MFMA on CDNA4). 268M MACs.
// R2 post-mortem: dur_us 80.26 with one 40.5us poison fill in the timed
// path -> kernel ~38us, 5x above the VALU-issue floor. Theory: per-j
// ds_read_b64 pairs with short use distance expose LDS latency at 2
// waves/SIMD, and 1.5 VALU-inst/MAC (scalar add+min).
// R3: j-contiguous LDS rows -> ds_read_b128 per 4j (4x fewer LDS insts),
// v_pk_add_f32 (<2 x float> adds) + v_min3_f32 (fminf(fminf(a,b),c))
// -> 1.0 VALU-inst/MAC. BK=128 (8 barriers total). 512 blocks, 2/CU.

typedef float v2f __attribute__((ext_vector_type(2)));

#define B_    512
#define IN_   512
#define OUT_  1024
#define TB    32
#define TO    32
#define BK    128
#define PADW  132   // floats per LDS row = 528B; %16==0 -> b128-aligned rows

__global__ __launch_bounds__(256, 2) void tropical_kernel(
    const float* __restrict__ x, const float* __restrict__ w,
    float* __restrict__ out)
{
    __shared__ float xs[TB * PADW];  // xs[b_local][j]  (row-major, padded)
    __shared__ float ws[TO * PADW];  // ws[o_local][j]

    const int tid = threadIdx.x;
    const int b0 = blockIdx.x * TB;
    const int o0 = blockIdx.y * TO;

    // staging: tile = 32 rows x 128 floats = 1024 float4s; 4 per thread
    const int scol  = tid & 31;   // float4 column (0..31)
    const int srow0 = tid >> 5;   // row 0..7, +8 per pass

    // compute: thread tile 2(b) x 2(o)
    const int to = tid & 15;
    const int tb = tid >> 4;
    const int rb = tb * 2;
    const int ro = to * 2;

    float acc00 = INFINITY, acc01 = INFINITY;
    float acc10 = INFINITY, acc11 = INFINITY;

    for (int k0 = 0; k0 < IN_; k0 += BK) {
        // ---- stage x tile (coalesced float4, b128 LDS stores) ----
#pragma unroll
        for (int p = 0; p < 4; ++p) {
            const int r = srow0 + p * 8;
            const float4 v = *(const float4*)&x[(size_t)(b0 + r) * IN_ + k0 + scol * 4];
            *(float4*)&xs[r * PADW + scol * 4] = v;
        }
        // ---- stage w tile ----
#pragma unroll
        for (int p = 0; p < 4; ++p) {
            const int r = srow0 + p * 8;
            const float4 v = *(const float4*)&w[(size_t)(o0 + r) * IN_ + k0 + scol * 4];
            *(float4*)&ws[r * PADW + scol * 4] = v;
        }
        __syncthreads();

        const float* xr0 = &xs[(rb + 0) * PADW];
        const float* xr1 = &xs[(rb + 1) * PADW];
        const float* wr0 = &ws[(ro + 0) * PADW];
        const float* wr1 = &ws[(ro + 1) * PADW];

        // ---- main loop: per 4j, 4x ds_read_b128 + 8 pk_add + 8 min3 ----
#pragma unroll 8
        for (int j = 0; j < BK; j += 4) {
            const float4 xa = *(const float4*)&xr0[j];
            const float4 xb = *(const float4*)&xr1[j];
            const float4 wa = *(const float4*)&wr0[j];
            const float4 wb = *(const float4*)&wr1[j];
            const v2f xa0 = {xa.x, xa.y}, xa1 = {xa.z, xa.w};
            const v2f xb0 = {xb.x, xb.y}, xb1 = {xb.z, xb.w};
            const v2f wa0 = {wa.x, wa.y}, wa1 = {wa.z, wa.w};
            const v2f wb0 = {wb.x, wb.y}, wb1 = {wb.z, wb.w};
            v2f t;
            t = xa0 + wa0; acc00 = fminf(fminf(acc00, t.x), t.y);
            t = xa1 + wa1; acc00 = fminf(fminf(acc00, t.x), t.y);
            t = xa0 + wb0; acc01 = fminf(fminf(acc01, t.x), t.y);
            t = xa1 + wb1; acc01 = fminf(fminf(acc01, t.x), t.y);
            t = xb0 + wa0; acc10 = fminf(fminf(acc10, t.x), t.y);
            t = xb1 + wa1; acc10 = fminf(fminf(acc10, t.x), t.y);
            t = xb0 + wb0; acc11 = fminf(fminf(acc11, t.x), t.y);
            t = xb1 + wb1; acc11 = fminf(fminf(acc11, t.x), t.y);
        }
        __syncthreads();
    }

    // ---- epilogue: two float2 stores per thread ----
    {
        v2f v0 = {acc00, acc01};
        *(v2f*)&out[(size_t)(b0 + rb + 0) * OUT_ + o0 + ro] = v0;
        v2f v1 = {acc10, acc11};
        *(v2f*)&out[(size_t)(b0 + rb + 1) * OUT_ + o0 + ro] = v1;
    }
}

extern "C" void kernel_launch(void* const* d_in, const int* in_sizes, int n_in,
                              void* d_out, int out_size, void* d_ws, size_t ws_size,
                              hipStream_t stream) {
    const float* x = (const float*)d_in[0];   // [512, 512]
    const float* w = (const float*)d_in[1];   // [1024, 512]
    float* out = (float*)d_out;               // [512, 1024]

    dim3 grid(B_ / TB, OUT_ / TO);            // 16 x 32 = 512 blocks, 2/CU
    tropical_kernel<<<grid, 256, 0, stream>>>(x, w, out);
}